// Round 1
// 333.564 us; speedup vs baseline: 1.0486x; 1.0486x over previous
//
#include <hip/hip_runtime.h>

// GCNConv forward: out = segment_sum(vals * (x@W)[cols], rows) + bias
// Round 8: attack fill_xcd's 5.3x scatter-write amplification (85us, VALU 0.8%,
// WRITE 67.8MB vs 12.8MB payload):
//  - XCD-major region layout (xcd*nb+bucket): each XCD appends into a
//    contiguous CAP=192 slab (2.4MB < 4MB per-XCD L2) so lines fill fully
//    in-cache and flush once.
//  - cursor counters padded to one 64B line each (no cross-XCD line sharing,
//    no same-line atomic serialization). 800KB, memset is trivial.
//  - non-temporal loads for the edge streams (no reuse -> don't evict the
//    resident bcv slab); NT on last-use bcv read in sort_gather.
//
// ws: h[N*128] bf16 | wt[128*264] bf16 | cursors[(NB*8)<<4 +16] int |
//     bcv[NB*8*CAP] int2 | ovf[OVFCAP] int4

typedef __attribute__((ext_vector_type(8))) short short8;
typedef __attribute__((ext_vector_type(4))) float floatx4;
typedef __attribute__((ext_vector_type(2))) int intv2;

#define WT_K 264
#define GM_NODES 128
#define BSHIFT 6              // 64 rows per bucket
#define BROWS 64
#define CAP 192               // records per (xcd,bucket) region; mean 128, 5.7 sigma
#define CSH 4                 // counters padded to 16 ints = one 64B line
#define OVFCAP 65536
// s_getreg imm: id=20 (HW_REG_XCC_ID), offset=0, size=4 -> (3<<11)|20
#define XCC_GETREG_IMM 6164

static __device__ __forceinline__ uint f2bf(float x) {  // RNE f32->bf16 bits
  uint u = __float_as_uint(x);
  return (u + 0x7fffu + ((u >> 16) & 1u)) >> 16;
}

// ---- W[k][f] f32 -> wt[f][k] bf16 (k padded to WT_K) ----
__global__ __launch_bounds__(256) void conv_w(const float* __restrict__ w,
                                              ushort* __restrict__ wt) {
  const int f = blockIdx.x;
  const int k = threadIdx.x;
  wt[f * WT_K + k] = (ushort)f2bf(w[k * 128 + f]);
}

// ---- GEMM: h^T = W^T x^T via 16x16x32 bf16 MFMA ----
__global__ __launch_bounds__(256) void gemm_mfma(const float* __restrict__ x,
                                                 const ushort* __restrict__ wt,
                                                 ushort* __restrict__ h,
                                                 int n_nodes) {
  __shared__ ushort lw[128 * WT_K];
  __shared__ ushort xa[GM_NODES * 40];
  const int t = threadIdx.x;
  const int lane = t & 63;
  const int wq = t >> 6;
  const int quad = lane >> 4;
  const int l15 = lane & 15;
  const int row0 = blockIdx.x * GM_NODES;

  {
    const uint4* src = (const uint4*)wt;
    uint4* dst = (uint4*)lw;
    for (int i = t; i < (128 * WT_K * 2) / 16; i += 256) dst[i] = src[i];
  }

  floatx4 acc[2][8];
#pragma unroll
  for (int nt = 0; nt < 2; ++nt)
#pragma unroll
    for (int mt = 0; mt < 8; ++mt) acc[nt][mt] = (floatx4){0.f, 0.f, 0.f, 0.f};

  float4 cur[4];
#pragma unroll
  for (int i = 0; i < 4; ++i) {
    const int idx = i * 256 + t;
    const int row = idx >> 3, kq = idx & 7;
    const int gr = row0 + row;
    cur[i] = (gr < n_nodes) ? *(const float4*)&x[(size_t)gr * 256 + kq * 4]
                            : make_float4(0.f, 0.f, 0.f, 0.f);
  }

  for (int kc = 0; kc < 8; ++kc) {
#pragma unroll
    for (int i = 0; i < 4; ++i) {
      const int idx = i * 256 + t;
      const int row = idx >> 3, kq = idx & 7;
      uint2 p;
      p.x = f2bf(cur[i].x) | (f2bf(cur[i].y) << 16);
      p.y = f2bf(cur[i].z) | (f2bf(cur[i].w) << 16);
      *(uint2*)&xa[row * 40 + kq * 4] = p;
    }
    __syncthreads();

    float4 nxt[4];
    if (kc < 7) {
#pragma unroll
      for (int i = 0; i < 4; ++i) {
        const int idx = i * 256 + t;
        const int row = idx >> 3, kq = idx & 7;
        const int gr = row0 + row;
        nxt[i] = (gr < n_nodes)
                     ? *(const float4*)&x[(size_t)gr * 256 + (kc + 1) * 32 + kq * 4]
                     : make_float4(0.f, 0.f, 0.f, 0.f);
      }
    }

    short8 bfr[2];
    bfr[0] = *(const short8*)&xa[(wq * 32 + l15) * 40 + quad * 8];
    bfr[1] = *(const short8*)&xa[(wq * 32 + 16 + l15) * 40 + quad * 8];
#pragma unroll
    for (int mt = 0; mt < 8; ++mt) {
      const short8 afr =
          *(const short8*)&lw[(mt * 16 + l15) * WT_K + kc * 32 + quad * 8];
      acc[0][mt] = __builtin_amdgcn_mfma_f32_16x16x32_bf16(afr, bfr[0],
                                                           acc[0][mt], 0, 0, 0);
      acc[1][mt] = __builtin_amdgcn_mfma_f32_16x16x32_bf16(afr, bfr[1],
                                                           acc[1][mt], 0, 0, 0);
    }
    __syncthreads();
#pragma unroll
    for (int i = 0; i < 4; ++i) cur[i] = nxt[i];
  }

#pragma unroll
  for (int nt = 0; nt < 2; ++nt) {
    const int node = row0 + wq * 32 + nt * 16 + l15;
    if (node < n_nodes) {
#pragma unroll
      for (int mt = 0; mt < 8; ++mt) {
        uint2 p;
        p.x = f2bf(acc[nt][mt][0]) | (f2bf(acc[nt][mt][1]) << 16);
        p.y = f2bf(acc[nt][mt][2]) | (f2bf(acc[nt][mt][3]) << 16);
        *(uint2*)&h[(size_t)node * 128 + mt * 16 + quad * 4] = p;
      }
    }
  }
}

// ---- append edges into (true-XCD, bucket) regions; rowoff packed in col ----
// XCD-major: region = xcd*nb + bucket -> per-XCD contiguous 2.4MB slab.
// Counters padded to one 64B line each.
__global__ __launch_bounds__(256) void fill_xcd(
    const int* __restrict__ erows, const int* __restrict__ ecols,
    const float* __restrict__ evals, int* __restrict__ cursors,
    int2* __restrict__ bcv, int* __restrict__ ovf_cnt,
    int4* __restrict__ ovf, int n_edges, int nb) {
  int i = blockIdx.x * 256 + threadIdx.x;
  if (i >= n_edges) return;
  const int xcd = (int)(__builtin_amdgcn_s_getreg(XCC_GETREG_IMM)) & 7;
  const int r = __builtin_nontemporal_load(&erows[i]);
  const int c = __builtin_nontemporal_load(&ecols[i]);
  const float v = __builtin_nontemporal_load(&evals[i]);
  const int reg = xcd * nb + (r >> BSHIFT);
  const int pos = atomicAdd(&cursors[reg << CSH], 1);
  if (pos < CAP) {
    int2 p;
    p.x = c | ((r & (BROWS - 1)) << 17);
    p.y = __float_as_int(v);
    bcv[(size_t)reg * CAP + pos] = p;
  } else {
    int op = atomicAdd(ovf_cnt, 1);
    if (op < OVFCAP) {
      int4 q; q.x = r; q.y = c; q.z = __float_as_int(v); q.w = 0;
      ovf[op] = q;
    }
  }
}

// ---- fused per-bucket counting sort (LDS) + node gather ----
// One block per bucket: sort <=1536 records into 12KB LDS, then 4 waves
// gather 16 nodes each (lane = feature pair), write dense out rows + bias.
__global__ __launch_bounds__(256) void sort_gather(
    const ushort* __restrict__ h, const int* __restrict__ cursors,
    const int2* __restrict__ bcv, const float* __restrict__ bias,
    float* __restrict__ out, int n_nodes, int nb) {
  __shared__ int2 buf[8 * CAP];            // 12 KB sorted records
  __shared__ int cnt[BROWS], start[BROWS], cur[BROWS];
  __shared__ int scnt[8];
  const int b = blockIdx.x;
  const int t = threadIdx.x;
  if (t < 8) scnt[t] = min(cursors[(t * nb + b) << CSH], CAP);
  if (t < BROWS) cnt[t] = 0;
  __syncthreads();

  // histogram of within-bucket row offsets (native int ds_add)
#pragma unroll
  for (int x = 0; x < 8; ++x) {
    const int n = scnt[x];
    const int2* src = &bcv[(size_t)(x * nb + b) * CAP];
    for (int i = t; i < n; i += 256) atomicAdd(&cnt[((uint)src[i].x) >> 17], 1);
  }
  __syncthreads();

  if (t < BROWS) {   // wave 0: 64-lane inclusive scan -> exclusive starts
    int c = cnt[t];
    int s = c;
#pragma unroll
    for (int off = 1; off < 64; off <<= 1) {
      int u = __shfl_up(s, off, 64);
      if (t >= off) s += u;
    }
    start[t] = s - c;
    cur[t] = s - c;
  }
  __syncthreads();

  // scatter into row-sorted LDS buffer (last use of bcv -> non-temporal)
#pragma unroll
  for (int x = 0; x < 8; ++x) {
    const int n = scnt[x];
    const intv2* src = (const intv2*)&bcv[(size_t)(x * nb + b) * CAP];
    for (int i = t; i < n; i += 256) {
      intv2 rr = __builtin_nontemporal_load(&src[i]);
      int2 rec; rec.x = rr[0]; rec.y = rr[1];
      int pos = atomicAdd(&cur[((uint)rec.x) >> 17], 1);
      buf[pos] = rec;
    }
  }
  __syncthreads();

  // gather: wave w handles rows w*16 .. w*16+15
  const int lane = t & 63;
  const int w = t >> 6;
  const float2 bv = ((const float2*)bias)[lane];
  for (int rr = w * 16; rr < w * 16 + 16; ++rr) {
    const int node = b * BROWS + rr;
    if (node >= n_nodes) break;
    float2 acc = bv;
    int p = start[rr];
    const int p1 = start[rr] + cnt[rr];
    for (; p + 4 <= p1; p += 4) {
      int2 e0 = buf[p + 0];
      int2 e1 = buf[p + 1];
      int2 e2 = buf[p + 2];
      int2 e3 = buf[p + 3];
      uint u0 = ((const uint*)(h + (size_t)(e0.x & 0x1FFFF) * 128))[lane];
      uint u1 = ((const uint*)(h + (size_t)(e1.x & 0x1FFFF) * 128))[lane];
      uint u2 = ((const uint*)(h + (size_t)(e2.x & 0x1FFFF) * 128))[lane];
      uint u3 = ((const uint*)(h + (size_t)(e3.x & 0x1FFFF) * 128))[lane];
      float v0 = __int_as_float(e0.y), v1 = __int_as_float(e1.y);
      float v2 = __int_as_float(e2.y), v3 = __int_as_float(e3.y);
      acc.x += v0 * __uint_as_float(u0 << 16);
      acc.y += v0 * __uint_as_float(u0 & 0xffff0000u);
      acc.x += v1 * __uint_as_float(u1 << 16);
      acc.y += v1 * __uint_as_float(u1 & 0xffff0000u);
      acc.x += v2 * __uint_as_float(u2 << 16);
      acc.y += v2 * __uint_as_float(u2 & 0xffff0000u);
      acc.x += v3 * __uint_as_float(u3 << 16);
      acc.y += v3 * __uint_as_float(u3 & 0xffff0000u);
    }
    for (; p < p1; ++p) {
      int2 ev = buf[p];
      float v = __int_as_float(ev.y);
      uint u = ((const uint*)(h + (size_t)(ev.x & 0x1FFFF) * 128))[lane];
      acc.x += v * __uint_as_float(u << 16);
      acc.y += v * __uint_as_float(u & 0xffff0000u);
    }
    ((float2*)(out + (size_t)node * 128))[lane] = acc;
  }
}

// ---- drain overflow spill list (expected near-empty; fixed grid for graph) ----
__global__ __launch_bounds__(256) void ovf_scatter(
    const ushort* __restrict__ h, const int* __restrict__ ovf_cnt,
    const int4* __restrict__ ovf, float* __restrict__ out) {
  const int n = min(*ovf_cnt, OVFCAP);
  const int lane = threadIdx.x & 63;
  const int wid = (blockIdx.x * 256 + threadIdx.x) >> 6;
  const int nw = gridDim.x * 4;
  for (int e = wid; e < n; e += nw) {
    int4 rec = ovf[e];
    float v = __int_as_float(rec.z);
    uint u = ((const uint*)(h + (size_t)rec.y * 128))[lane];
    float* op = out + (size_t)rec.x * 128 + lane * 2;
    atomicAdd(op, v * __uint_as_float(u << 16));
    atomicAdd(op + 1, v * __uint_as_float(u & 0xffff0000u));
  }
}

// ---- fallback (small ws): bias init + atomic scatter on bf16 h ----
__global__ __launch_bounds__(256) void init_bias(float* __restrict__ out,
                                                 const float* __restrict__ bias,
                                                 int n4) {
  int i = blockIdx.x * 256 + threadIdx.x;
  if (i < n4) {
    float4 b = ((const float4*)bias)[i & 31];
    ((float4*)out)[i] = b;
  }
}

__global__ __launch_bounds__(256) void scatter_edges(
    const ushort* __restrict__ h, const int* __restrict__ erows,
    const int* __restrict__ ecols, const float* __restrict__ evals,
    float* __restrict__ out, int n_edges) {
  int e = blockIdx.x * 4 + (threadIdx.x >> 6);
  if (e >= n_edges) return;
  int lane = threadIdx.x & 63;
  int row = erows[e];
  int col = ecols[e];
  float v = evals[e];
  uint u = ((const uint*)(h + (size_t)col * 128))[lane];
  float* op = out + (size_t)row * 128 + lane * 2;
  atomicAdd(op, v * __uint_as_float(u << 16));
  atomicAdd(op + 1, v * __uint_as_float(u & 0xffff0000u));
}

extern "C" void kernel_launch(void* const* d_in, const int* in_sizes, int n_in,
                              void* d_out, int out_size, void* d_ws, size_t ws_size,
                              hipStream_t stream) {
  const float* x     = (const float*)d_in[0];
  const int*   erows = (const int*)d_in[1];
  const int*   ecols = (const int*)d_in[2];
  const float* evals = (const float*)d_in[3];
  const float* w     = (const float*)d_in[4];
  const float* bias  = (const float*)d_in[5];
  float* out = (float*)d_out;

  const int n_nodes = in_sizes[0] / 256;
  const int n_edges = in_sizes[1];
  const int nb_buckets = (n_nodes + BROWS - 1) >> BSHIFT;
  const int nb8 = nb_buckets * 8;

  // ws carve-up (256B aligned so bcv regions are line-aligned)
  char* ws = (char*)d_ws;
  size_t off = 0;
  ushort* h  = (ushort*)(ws + off);  off += ((size_t)n_nodes * 128 * 2 + 255) & ~255ull;
  ushort* wt = (ushort*)(ws + off);  off += ((size_t)128 * WT_K * 2 + 255) & ~255ull;
  const size_t cur_ints = (((size_t)nb8) << CSH) + 16;   // + ovf_cnt slot
  int* cursors = (int*)(ws + off);   off += (cur_ints * 4 + 255) & ~255ull;
  int2* bcv    = (int2*)(ws + off);  off += ((size_t)nb8 * CAP * 8 + 255) & ~255ull;
  int4* ovf    = (int4*)(ws + off);  off += (size_t)OVFCAP * 16;
  const bool bucket_ok = (off <= ws_size) && (n_nodes <= (1 << 17));
  int* ovf_cnt = cursors + (((size_t)nb8) << CSH);

  conv_w<<<128, 256, 0, stream>>>(w, wt);
  const int gemm_blocks = (n_nodes + GM_NODES - 1) / GM_NODES;
  gemm_mfma<<<gemm_blocks, 256, 0, stream>>>(x, wt, h, n_nodes);

  if (bucket_ok) {
    hipMemsetAsync(cursors, 0, cur_ints * 4, stream);
    const int eblocks = (n_edges + 255) / 256;
    fill_xcd<<<eblocks, 256, 0, stream>>>(erows, ecols, evals, cursors, bcv,
                                          ovf_cnt, ovf, n_edges, nb_buckets);
    sort_gather<<<nb_buckets, 256, 0, stream>>>(h, cursors, bcv, bias, out,
                                                n_nodes, nb_buckets);
    ovf_scatter<<<32, 256, 0, stream>>>(h, ovf_cnt, ovf, out);
  } else {
    const int n4 = out_size / 4;
    init_bias<<<(n4 + 255) / 256, 256, 0, stream>>>(out, bias, n4);
    scatter_edges<<<(n_edges + 3) / 4, 256, 0, stream>>>(h, erows, ecols, evals,
                                                         out, n_edges);
  }
}